// Round 7
// baseline (188.444 us; speedup 1.0000x reference)
//
#include <hip/hip_runtime.h>

typedef __attribute__((ext_vector_type(8))) short bf16x8;
typedef __attribute__((ext_vector_type(4))) float f32x4;

constexpr int NN = 50000;          // nodes
constexpr int NE = 800000;         // edges
constexpr int C1 = 128;            // in/hidden channels
constexpr int C2 = 64;             // out channels
constexpr int NBK = 196;           // dst buckets of 256 nodes
constexpr int EPB = 2048;          // edges per bin block
constexpr int NBLK = (NE + EPB - 1) / EPB;   // 391
constexpr int MT = NN / 16;        // 3125 M-tiles (exact)
constexpr int CAP = 8192;          // LDS edge cache per bucket
constexpr int GB = (NN + 3) / 4;   // 12500 gather2 blocks (4 waves = 4 nodes each)

constexpr int K1G = 1024;                    // K1 grid: 391 bin + 633 mm1 blocks
constexpr int MM1_NW = (K1G - NBLK) * 4;     // 2532 mm1 waves
constexpr int K3G = 1792;                    // K3 grid (grid-stride over MT tiles)

// float -> bf16 round-to-nearest-even
__device__ __forceinline__ unsigned short f2bf(float f) {
    unsigned int u = __float_as_uint(f);
    u += 0x7FFFu + ((u >> 16) & 1u);
    return (unsigned short)(u >> 16);
}
// packed bf16 pair -> two floats (low ushort = even element)
__device__ __forceinline__ float2 bf2f(unsigned int u) {
    return make_float2(__uint_as_float(u << 16), __uint_as_float(u & 0xFFFF0000u));
}
__device__ __forceinline__ unsigned int pk2(float a, float b) {
    return (unsigned int)f2bf(a) | ((unsigned int)f2bf(b) << 16);
}
__device__ __forceinline__ bf16x8 pack8(float4 a, float4 b) {
    bf16x8 r;
    r[0] = (short)f2bf(a.x); r[1] = (short)f2bf(a.y);
    r[2] = (short)f2bf(a.z); r[3] = (short)f2bf(a.w);
    r[4] = (short)f2bf(b.x); r[5] = (short)f2bf(b.y);
    r[6] = (short)f2bf(b.z); r[7] = (short)f2bf(b.w);
    return r;
}

struct BinSmem {                    // 10,784 B
    int lhist[NBK];
    int ls[256];
    int lcur[NBK];
    unsigned int lbuf[EPB];
};

// ---------------- K1a: CSR pass 1 — per-block counting sort by coarse bucket ----------------
__device__ void bin_work(const int* __restrict__ src, const int* __restrict__ dst,
                         unsigned int* __restrict__ ebuf, int* __restrict__ localOff,
                         BinSmem& S) {
    const int t = threadIdx.x;
    const int base = blockIdx.x * EPB;
    if (t < NBK) S.lhist[t] = 0;
    __syncthreads();
    int b[8]; unsigned int p[8];
    #pragma unroll
    for (int i = 0; i < 8; i++) {
        int e = base + i * 256 + t;
        if (e < NE) {
            int s = src[e], d = dst[e];
            b[i] = d >> 8;
            p[i] = ((unsigned int)(d & 255) << 16) | (unsigned int)s;
            atomicAdd(&S.lhist[b[i]], 1);
        } else b[i] = -1;
    }
    __syncthreads();
    int v = (t < NBK) ? S.lhist[t] : 0;
    S.ls[t] = v;
    __syncthreads();
    #pragma unroll
    for (int d = 1; d < 256; d <<= 1) {
        int u = (t >= d) ? S.ls[t - d] : 0;
        __syncthreads();
        S.ls[t] += u;
        __syncthreads();
    }
    if (t < NBK) {
        S.lcur[t] = S.ls[t] - v;
        localOff[blockIdx.x * 200 + t] = S.ls[t] - v;
    }
    if (t == NBK - 1) localOff[blockIdx.x * 200 + NBK] = S.ls[t];
    __syncthreads();
    #pragma unroll
    for (int i = 0; i < 8; i++) {
        if (b[i] >= 0) {
            int lp = atomicAdd(&S.lcur[b[i]], 1);
            S.lbuf[lp] = p[i];
        }
    }
    __syncthreads();
    #pragma unroll
    for (int i = 0; i < 8; i++)
        ebuf[base + i * 256 + t] = S.lbuf[i * 256 + t];   // tail garbage never read
}

// ---------------- K1b: mm1 — g1(bf16 row-major) = x @ W1 UNSCALED ---------------------------
// dinv doesn't exist yet (CSR building concurrently); place_kernel folds dinv into g1 later.
__device__ void mm1_work(const float* __restrict__ x, const float* __restrict__ W,
                         unsigned short* __restrict__ g1,
                         unsigned short (&wl)[4][8][64][8]) {
    const int t = threadIdx.x;
    for (int i = 0; i < 64; i++) {
        int idx = i * 256 + t;
        int k = idx >> 7, n = idx & 127;
        wl[k >> 5][n >> 4][((k >> 3) & 3) * 16 + (n & 15)][k & 7] = f2bf(W[idx]);
    }
    __syncthreads();
    const int lane = t & 63, lm = lane & 15, quad = lane >> 4;

    bf16x8 bfr[4][8];
    #pragma unroll
    for (int s = 0; s < 4; s++)
        #pragma unroll
        for (int nt = 0; nt < 8; nt++)
            bfr[s][nt] = *(const bf16x8*)&wl[s][nt][lane][0];

    const int widx = (blockIdx.x - NBLK) * 4 + (t >> 6);
    for (int tile = widx; tile < MT; tile += MM1_NW) {
        int row0 = tile << 4;
        const float* xr = x + (size_t)(row0 + lm) * 128 + quad * 8;
        bf16x8 af[4];
        #pragma unroll
        for (int s = 0; s < 4; s++) {
            float4 p = *(const float4*)(xr + s * 32);
            float4 q = *(const float4*)(xr + s * 32 + 4);
            af[s] = pack8(p, q);
        }
        f32x4 acc[8];
        #pragma unroll
        for (int nt = 0; nt < 8; nt++) acc[nt] = (f32x4){0.f, 0.f, 0.f, 0.f};
        #pragma unroll
        for (int s = 0; s < 4; s++)
            #pragma unroll
            for (int nt = 0; nt < 8; nt++)
                acc[nt] = __builtin_amdgcn_mfma_f32_16x16x32_bf16(af[s], bfr[s][nt],
                                                                  acc[nt], 0, 0, 0);
        #pragma unroll
        for (int nt = 0; nt < 8; nt++)
            #pragma unroll
            for (int r = 0; r < 4; r++)
                g1[(size_t)(row0 + quad * 4 + r) * 128 + nt * 16 + lm] = f2bf(acc[nt][r]);
    }
}

// ---------------- K1: bin (blocks [0,391)) || mm1 (blocks [391,1024)) -----------------------
__global__ __launch_bounds__(256, 2) void k1_kernel(const int* __restrict__ src,
                                                    const int* __restrict__ dst,
                                                    unsigned int* __restrict__ ebuf,
                                                    int* __restrict__ localOff,
                                                    const float* __restrict__ x,
                                                    const float* __restrict__ W1,
                                                    unsigned short* __restrict__ g1) {
    __shared__ union { BinSmem b; unsigned short wl[4][8][64][8]; } sm;   // 32 KB
    if (blockIdx.x < NBLK) bin_work(src, dst, ebuf, localOff, sm.b);
    else                   mm1_work(x, W1, g1, sm.wl);
}

// ---------------- K2: place + fold dinv into this bucket's g1 rows --------------------------
__global__ __launch_bounds__(256) void place_kernel(const unsigned int* __restrict__ ebuf,
                                                    const int* __restrict__ localOff,
                                                    unsigned short* __restrict__ esrc,
                                                    int* __restrict__ cnt,
                                                    int* __restrict__ off,
                                                    float* __restrict__ dinv,
                                                    unsigned short* __restrict__ g1) {
    __shared__ unsigned int lbuf[CAP];   // 32 KB
    __shared__ int lhist[256];
    __shared__ int ls[256];
    __shared__ int lcur[256];
    __shared__ int red[256];
    const int t = threadIdx.x;
    const int bkt = blockIdx.x;
    const int node0 = bkt << 8;
    const int nnodes = min(256, NN - node0);

    const int j0 = 2 * t, j1 = 2 * t + 1;
    int s0 = 0, l0 = 0, s1 = 0, l1 = 0;
    if (j0 < NBLK) { s0 = localOff[j0 * 200 + bkt]; l0 = localOff[j0 * 200 + bkt + 1] - s0; }
    if (j1 < NBLK) { s1 = localOff[j1 * 200 + bkt]; l1 = localOff[j1 * 200 + bkt + 1] - s1; }

    red[t] = s0 + s1;          // -> segBase (sum of chunk-local exclusive prefixes)
    ls[t] = l0 + l1;           // -> lbuf base scan
    lhist[t] = 0;
    __syncthreads();
    #pragma unroll
    for (int d = 1; d < 256; d <<= 1) {
        int u = (t >= d) ? ls[t - d] : 0;
        int r = (t + d < 256) ? red[t + d] : 0;
        __syncthreads();
        ls[t] += u;
        red[t] += r;
        __syncthreads();
    }
    const int segBase = red[0];
    const int total = ls[255];
    const int base0 = ls[t] - (l0 + l1);
    const int base1 = base0 + l0;
    const bool fits = (total <= CAP);

    if (fits) {
        const unsigned int* q0 = ebuf + j0 * EPB + s0;
        for (int k = 0; k < l0; k++) lbuf[base0 + k] = q0[k];
        const unsigned int* q1 = ebuf + j1 * EPB + s1;
        for (int k = 0; k < l1; k++) lbuf[base1 + k] = q1[k];
        __syncthreads();
        for (int k = t; k < total; k += 256) atomicAdd(&lhist[lbuf[k] >> 16], 1);
    } else {
        const unsigned int* q0 = ebuf + j0 * EPB + s0;
        for (int k = 0; k < l0; k++) atomicAdd(&lhist[q0[k] >> 16], 1);
        const unsigned int* q1 = ebuf + j1 * EPB + s1;
        for (int k = 0; k < l1; k++) atomicAdd(&lhist[q1[k] >> 16], 1);
    }
    __syncthreads();
    int v = lhist[t];
    ls[t] = v;
    __syncthreads();
    #pragma unroll
    for (int d = 1; d < 256; d <<= 1) {
        int u = (t >= d) ? ls[t - d] : 0;
        __syncthreads();
        ls[t] += u;
        __syncthreads();
    }
    int ex = ls[t] - v;
    lcur[t] = ex;
    if (t < nnodes) {
        cnt[node0 + t] = v;
        off[node0 + t] = segBase + ex;
        dinv[node0 + t] = rsqrtf((float)v + 1.0f);
    }
    __syncthreads();
    if (fits) {
        for (int k = t; k < total; k += 256) {
            unsigned int pp = lbuf[k];
            int lp = atomicAdd(&lcur[pp >> 16], 1);
            esrc[segBase + lp] = (unsigned short)(pp & 0xFFFFu);
        }
    } else {
        const unsigned int* q0 = ebuf + j0 * EPB + s0;
        for (int k = 0; k < l0; k++) {
            unsigned int pp = q0[k];
            int lp = atomicAdd(&lcur[pp >> 16], 1);
            esrc[segBase + lp] = (unsigned short)(pp & 0xFFFFu);
        }
        const unsigned int* q1 = ebuf + j1 * EPB + s1;
        for (int k = 0; k < l1; k++) {
            unsigned int pp = q1[k];
            int lp = atomicAdd(&lcur[pp >> 16], 1);
            esrc[segBase + lp] = (unsigned short)(pp & 0xFFFFu);
        }
    }
    // fold dinv into this bucket's g1 rows (coalesced 256 B per row-pass).
    // dinv[node0+r] was written pre-scatter by this block; same-CU L1 serves it.
    const int w = t >> 6, lane = t & 63;
    unsigned int* g1u = (unsigned int*)g1;
    for (int r = w; r < nnodes; r += 4) {
        const float dn = dinv[node0 + r];
        const size_t a = (size_t)(node0 + r) * 64 + lane;
        float2 p = bf2f(g1u[a]);
        g1u[a] = pk2(dn * p.x, dn * p.y);
    }
}

// ---------------- K3: fused gather1 + mm2 per 16-node tile ----------------------------------
// 4 waves x 4 nodes: wave-per-node whole-row coalesced gather (g1 rows pre-scaled by dinv[s]),
// bias+ReLU, x2 row -> LDS tile (never global). Sync. Wave w computes mm2 quadrant nt=w from
// the LDS tile and writes dinv-scaled g2.
__global__ __launch_bounds__(256) void gmm_kernel(const unsigned short* __restrict__ g1,
                                                  const unsigned short* __restrict__ esrc,
                                                  const int* __restrict__ off,
                                                  const int* __restrict__ cnt,
                                                  const float* __restrict__ dinv,
                                                  const float* __restrict__ b1,
                                                  const float* __restrict__ W2,
                                                  unsigned short* __restrict__ g2) {
    __shared__ unsigned short wl2[4][4][64][8];   // 16 KB, W2 B-fragments
    __shared__ unsigned short x2t[16][136];       // x2 tile, row pad -> 272 B stride
    const int t = threadIdx.x;
    for (int i = 0; i < 32; i++) {                // stage W2 (8192 elems)
        int idx = i * 256 + t;
        int k = idx >> 6, n = idx & 63;
        wl2[k >> 5][n >> 4][((k >> 3) & 3) * 16 + (n & 15)][k & 7] = f2bf(W2[idx]);
    }
    const int lane = t & 63, w = t >> 6, lm = lane & 15, quad = lane >> 4;
    const unsigned int* G = (const unsigned int*)g1;   // row stride 64 uints (256 B)
    const float2 bb = ((const float2*)b1)[lane];

    for (int tile = blockIdx.x; tile < MT; tile += K3G) {
        __syncthreads();   // W2 staged (iter 0) / prior MFMA x2t reads done (iter >0)
        #pragma unroll 1
        for (int k4 = 0; k4 < 4; k4++) {
            const int n = tile * 16 + w * 4 + k4;
            float2 ps = bf2f(G[(size_t)n * 64 + lane]);   // self-loop
            float a0 = ps.x, a1 = ps.y;
            float c0 = 0.f, c1 = 0.f;
            const int s0 = off[n], c = cnt[n];
            for (int base = 0; base < c; base += 64) {
                const int m = min(64, c - base);
                int vidx = 0;
                if (lane < m) vidx = esrc[s0 + base + lane];   // coalesced index batch
                int i = 0;
                for (; i + 3 < m; i += 4) {
                    int sA = __shfl(vidx, i),     sB = __shfl(vidx, i + 1);
                    int sC = __shfl(vidx, i + 2), sD = __shfl(vidx, i + 3);
                    unsigned int vA = G[(size_t)sA * 64 + lane];
                    unsigned int vB = G[(size_t)sB * 64 + lane];
                    unsigned int vC = G[(size_t)sC * 64 + lane];
                    unsigned int vD = G[(size_t)sD * 64 + lane];
                    float2 pA = bf2f(vA); a0 += pA.x; a1 += pA.y;
                    float2 pB = bf2f(vB); c0 += pB.x; c1 += pB.y;
                    float2 pC = bf2f(vC); a0 += pC.x; a1 += pC.y;
                    float2 pD = bf2f(vD); c0 += pD.x; c1 += pD.y;
                }
                for (; i < m; i++) {
                    int sA = __shfl(vidx, i);
                    float2 pA = bf2f(G[(size_t)sA * 64 + lane]);
                    a0 += pA.x; a1 += pA.y;
                }
            }
            a0 += c0; a1 += c1;
            const float sc = dinv[n];
            const float o0 = fmaxf(sc * a0 + bb.x, 0.f);
            const float o1 = fmaxf(sc * a1 + bb.y, 0.f);
            ((unsigned int*)&x2t[w * 4 + k4][0])[lane] = pk2(o0, o1);
        }
        __syncthreads();
        // mm2 quadrant nt = w for this tile
        const int row0 = tile << 4;
        bf16x8 af[4];
        #pragma unroll
        for (int s = 0; s < 4; s++)
            af[s] = *(const bf16x8*)&x2t[lm][quad * 8 + s * 32];
        f32x4 acc = (f32x4){0.f, 0.f, 0.f, 0.f};
        #pragma unroll
        for (int s = 0; s < 4; s++) {
            bf16x8 bfr = *(const bf16x8*)&wl2[s][w][lane][0];
            acc = __builtin_amdgcn_mfma_f32_16x16x32_bf16(af[s], bfr, acc, 0, 0, 0);
        }
        float4 dv = *(const float4*)(dinv + row0 + quad * 4);
        float dvv[4] = {dv.x, dv.y, dv.z, dv.w};
        #pragma unroll
        for (int r = 0; r < 4; r++)
            g2[(size_t)(row0 + quad * 4 + r) * 64 + w * 16 + lm] = f2bf(acc[r] * dvv[r]);
    }
}

// ---------------- K4: gather2 — wave-per-node whole-row (128 B) coalesced, fp32 out ---------
__global__ __launch_bounds__(256) void gather2_kernel(const unsigned short* __restrict__ g2,
                                                      const unsigned short* __restrict__ esrc,
                                                      const int* __restrict__ off,
                                                      const int* __restrict__ cnt,
                                                      const float* __restrict__ dinv,
                                                      const float* __restrict__ b2,
                                                      float* __restrict__ out) {
    const int n = blockIdx.x * 4 + (threadIdx.x >> 6);
    if (n >= NN) return;
    const int lane = threadIdx.x & 63;
    const unsigned short* G = g2;                      // row stride 64 ushorts (128 B)
    float a0 = __uint_as_float((unsigned int)G[(size_t)n * 64 + lane] << 16);  // self-loop
    float c0 = 0.f;
    const int s0 = off[n], c = cnt[n];
    for (int base = 0; base < c; base += 64) {
        const int m = min(64, c - base);
        int vidx = 0;
        if (lane < m) vidx = esrc[s0 + base + lane];
        int i = 0;
        for (; i + 3 < m; i += 4) {
            int sA = __shfl(vidx, i),     sB = __shfl(vidx, i + 1);
            int sC = __shfl(vidx, i + 2), sD = __shfl(vidx, i + 3);
            unsigned short vA = G[(size_t)sA * 64 + lane];
            unsigned short vB = G[(size_t)sB * 64 + lane];
            unsigned short vC = G[(size_t)sC * 64 + lane];
            unsigned short vD = G[(size_t)sD * 64 + lane];
            a0 += __uint_as_float((unsigned int)vA << 16);
            c0 += __uint_as_float((unsigned int)vB << 16);
            a0 += __uint_as_float((unsigned int)vC << 16);
            c0 += __uint_as_float((unsigned int)vD << 16);
        }
        for (; i < m; i++) {
            int sA = __shfl(vidx, i);
            a0 += __uint_as_float((unsigned int)G[(size_t)sA * 64 + lane] << 16);
        }
    }
    a0 += c0;
    out[(size_t)n * 64 + lane] = dinv[n] * a0 + b2[lane];   // 256 B coalesced store
}

extern "C" void kernel_launch(void* const* d_in, const int* in_sizes, int n_in,
                              void* d_out, int out_size, void* d_ws, size_t ws_size,
                              hipStream_t stream) {
    const float* x  = (const float*)d_in[0];
    const int* edges = (const int*)d_in[1];     // [2, NE] int32
    const float* W1 = (const float*)d_in[2];
    const float* b1 = (const float*)d_in[3];
    const float* W2 = (const float*)d_in[4];
    const float* b2 = (const float*)d_in[5];
    const int* src = edges;
    const int* dst = edges + NE;

    // workspace layout (all chunks 16B-aligned)
    int* localOff  = (int*)d_ws;                        // NBLK*200 = 78200, pad 78208
    unsigned int* ebuf = (unsigned int*)(localOff + 78208);   // NBLK*EPB = 800768
    unsigned short* esrc = (unsigned short*)(ebuf + (size_t)NBLK * EPB);  // 800000 u16, pad 800768
    int* cnt       = (int*)(esrc + 800768);             // 50048
    int* off       = cnt + 50048;                       // 50048
    float* dinv    = (float*)(off + 50048);             // 50048
    unsigned short* g1 = (unsigned short*)(dinv + 50048);   // [NN][128] bf16 (raw, then dinv-scaled by K2)
    unsigned short* g2 = g1 + (size_t)NN * C1;              // [NN][64] bf16 (dinv-scaled)
    float* out = (float*)d_out;

    // K1: CSR bin || all of mm1 (g1 unscaled -> independent of CSR)
    k1_kernel<<<K1G, 256, 0, stream>>>(src, dst, ebuf, localOff, x, W1, g1);
    // K2: CSR place (esrc/cnt/off/dinv) + fold dinv into g1 rows
    place_kernel<<<NBK, 256, 0, stream>>>(ebuf, localOff, esrc, cnt, off, dinv, g1);
    // K3: fused gather1 + mm2 (x2 lives only in LDS)
    gmm_kernel<<<K3G, 256, 0, stream>>>(g1, esrc, off, cnt, dinv, b1, W2, g2);
    // K4: gather2 -> out
    gather2_kernel<<<GB, 256, 0, stream>>>(g2, esrc, off, cnt, dinv, b2, out);
}

// Round 8
// 178.958 us; speedup vs baseline: 1.0530x; 1.0530x over previous
//
#include <hip/hip_runtime.h>

typedef __attribute__((ext_vector_type(8))) short bf16x8;
typedef __attribute__((ext_vector_type(4))) float f32x4;

constexpr int NN = 50000;          // nodes
constexpr int NE = 800000;         // edges
constexpr int C1 = 128;            // in/hidden channels
constexpr int C2 = 64;             // out channels
constexpr int NBK = 196;           // dst buckets of 256 nodes
constexpr int EPB = 2048;          // edges per bin block
constexpr int NBLK = (NE + EPB - 1) / EPB;   // 391
constexpr int MT = NN / 16;        // 3125 M-tiles (exact)
constexpr int CAP = 8192;          // LDS edge cache per bucket
constexpr int GB = (NN + 3) / 4;   // 12500 gather blocks (4 waves = 4 nodes each)
constexpr int MMB = 500;           // mm2 blocks: 2 blocks/CU
constexpr int MMWAVES = MMB * 4;

constexpr int K1G = 1024;                    // K1 grid: 391 bin + 633 mm1 blocks
constexpr int MM1_NW = (K1G - NBLK) * 4;     // 2532 mm1 waves

// float -> bf16 round-to-nearest-even
__device__ __forceinline__ unsigned short f2bf(float f) {
    unsigned int u = __float_as_uint(f);
    u += 0x7FFFu + ((u >> 16) & 1u);
    return (unsigned short)(u >> 16);
}
// packed bf16 pair -> two floats (low ushort = even element)
__device__ __forceinline__ float2 bf2f(unsigned int u) {
    return make_float2(__uint_as_float(u << 16), __uint_as_float(u & 0xFFFF0000u));
}
__device__ __forceinline__ unsigned int pk2(float a, float b) {
    return (unsigned int)f2bf(a) | ((unsigned int)f2bf(b) << 16);
}
__device__ __forceinline__ bf16x8 pack8(float4 a, float4 b) {
    bf16x8 r;
    r[0] = (short)f2bf(a.x); r[1] = (short)f2bf(a.y);
    r[2] = (short)f2bf(a.z); r[3] = (short)f2bf(a.w);
    r[4] = (short)f2bf(b.x); r[5] = (short)f2bf(b.y);
    r[6] = (short)f2bf(b.z); r[7] = (short)f2bf(b.w);
    return r;
}

struct BinSmem {                    // 10,784 B
    int lhist[NBK];
    int ls[256];
    int lcur[NBK];
    unsigned int lbuf[EPB];
};

// ---------------- K1a: CSR pass 1 — per-block counting sort by coarse bucket ----------------
__device__ void bin_work(const int* __restrict__ src, const int* __restrict__ dst,
                         unsigned int* __restrict__ ebuf, int* __restrict__ localOff,
                         BinSmem& S) {
    const int t = threadIdx.x;
    const int base = blockIdx.x * EPB;
    if (t < NBK) S.lhist[t] = 0;
    __syncthreads();
    int b[8]; unsigned int p[8];
    #pragma unroll
    for (int i = 0; i < 8; i++) {
        int e = base + i * 256 + t;
        if (e < NE) {
            int s = src[e], d = dst[e];
            b[i] = d >> 8;
            p[i] = ((unsigned int)(d & 255) << 16) | (unsigned int)s;
            atomicAdd(&S.lhist[b[i]], 1);
        } else b[i] = -1;
    }
    __syncthreads();
    int v = (t < NBK) ? S.lhist[t] : 0;
    S.ls[t] = v;
    __syncthreads();
    #pragma unroll
    for (int d = 1; d < 256; d <<= 1) {
        int u = (t >= d) ? S.ls[t - d] : 0;
        __syncthreads();
        S.ls[t] += u;
        __syncthreads();
    }
    if (t < NBK) {
        S.lcur[t] = S.ls[t] - v;
        localOff[blockIdx.x * 200 + t] = S.ls[t] - v;
    }
    if (t == NBK - 1) localOff[blockIdx.x * 200 + NBK] = S.ls[t];
    __syncthreads();
    #pragma unroll
    for (int i = 0; i < 8; i++) {
        if (b[i] >= 0) {
            int lp = atomicAdd(&S.lcur[b[i]], 1);
            S.lbuf[lp] = p[i];
        }
    }
    __syncthreads();
    #pragma unroll
    for (int i = 0; i < 8; i++)
        ebuf[base + i * 256 + t] = S.lbuf[i * 256 + t];   // tail garbage never read
}

// ---------------- K1b: mm1 — g1(bf16 row-major) = x @ W1 UNSCALED ---------------------------
// dinv doesn't exist yet (CSR builds concurrently); gather1 applies dinv per edge.
__device__ void mm1_work(const float* __restrict__ x, const float* __restrict__ W,
                         unsigned short* __restrict__ g1,
                         unsigned short (&wl)[4][8][64][8]) {
    const int t = threadIdx.x;
    for (int i = 0; i < 64; i++) {
        int idx = i * 256 + t;
        int k = idx >> 7, n = idx & 127;
        wl[k >> 5][n >> 4][((k >> 3) & 3) * 16 + (n & 15)][k & 7] = f2bf(W[idx]);
    }
    __syncthreads();
    const int lane = t & 63, lm = lane & 15, quad = lane >> 4;

    bf16x8 bfr[4][8];
    #pragma unroll
    for (int s = 0; s < 4; s++)
        #pragma unroll
        for (int nt = 0; nt < 8; nt++)
            bfr[s][nt] = *(const bf16x8*)&wl[s][nt][lane][0];

    const int widx = (blockIdx.x - NBLK) * 4 + (t >> 6);
    for (int tile = widx; tile < MT; tile += MM1_NW) {
        int row0 = tile << 4;
        const float* xr = x + (size_t)(row0 + lm) * 128 + quad * 8;
        bf16x8 af[4];
        #pragma unroll
        for (int s = 0; s < 4; s++) {
            float4 p = *(const float4*)(xr + s * 32);
            float4 q = *(const float4*)(xr + s * 32 + 4);
            af[s] = pack8(p, q);
        }
        f32x4 acc[8];
        #pragma unroll
        for (int nt = 0; nt < 8; nt++) acc[nt] = (f32x4){0.f, 0.f, 0.f, 0.f};
        #pragma unroll
        for (int s = 0; s < 4; s++)
            #pragma unroll
            for (int nt = 0; nt < 8; nt++)
                acc[nt] = __builtin_amdgcn_mfma_f32_16x16x32_bf16(af[s], bfr[s][nt],
                                                                  acc[nt], 0, 0, 0);
        #pragma unroll
        for (int nt = 0; nt < 8; nt++)
            #pragma unroll
            for (int r = 0; r < 4; r++)
                g1[(size_t)(row0 + quad * 4 + r) * 128 + nt * 16 + lm] = f2bf(acc[nt][r]);
    }
}

// ---------------- K1: bin (blocks [0,391)) || mm1 (blocks [391,1024)) -----------------------
__global__ __launch_bounds__(256, 2) void k1_kernel(const int* __restrict__ src,
                                                    const int* __restrict__ dst,
                                                    unsigned int* __restrict__ ebuf,
                                                    int* __restrict__ localOff,
                                                    const float* __restrict__ x,
                                                    const float* __restrict__ W1,
                                                    unsigned short* __restrict__ g1) {
    __shared__ union { BinSmem b; unsigned short wl[4][8][64][8]; } sm;   // 32 KB
    if (blockIdx.x < NBLK) bin_work(src, dst, ebuf, localOff, sm.b);
    else                   mm1_work(x, W1, g1, sm.wl);
}

// ---------------- K2: CSR pass 2 — one block per bucket, bucket edges cached in LDS ---------
__global__ __launch_bounds__(256) void place_kernel(const unsigned int* __restrict__ ebuf,
                                                    const int* __restrict__ localOff,
                                                    unsigned short* __restrict__ esrc,
                                                    int* __restrict__ cnt,
                                                    int* __restrict__ off,
                                                    float* __restrict__ dinv) {
    __shared__ unsigned int lbuf[CAP];   // 32 KB
    __shared__ int lhist[256];
    __shared__ int ls[256];
    __shared__ int lcur[256];
    __shared__ int red[256];
    const int t = threadIdx.x;
    const int bkt = blockIdx.x;
    const int node0 = bkt << 8;
    const int nnodes = min(256, NN - node0);

    const int j0 = 2 * t, j1 = 2 * t + 1;
    int s0 = 0, l0 = 0, s1 = 0, l1 = 0;
    if (j0 < NBLK) { s0 = localOff[j0 * 200 + bkt]; l0 = localOff[j0 * 200 + bkt + 1] - s0; }
    if (j1 < NBLK) { s1 = localOff[j1 * 200 + bkt]; l1 = localOff[j1 * 200 + bkt + 1] - s1; }

    red[t] = s0 + s1;          // -> segBase (sum of chunk-local exclusive prefixes)
    ls[t] = l0 + l1;           // -> lbuf base scan
    lhist[t] = 0;
    __syncthreads();
    #pragma unroll
    for (int d = 1; d < 256; d <<= 1) {
        int u = (t >= d) ? ls[t - d] : 0;
        int r = (t + d < 256) ? red[t + d] : 0;
        __syncthreads();
        ls[t] += u;
        red[t] += r;
        __syncthreads();
    }
    const int segBase = red[0];
    const int total = ls[255];
    const int base0 = ls[t] - (l0 + l1);
    const int base1 = base0 + l0;
    const bool fits = (total <= CAP);

    if (fits) {
        const unsigned int* q0 = ebuf + j0 * EPB + s0;
        for (int k = 0; k < l0; k++) lbuf[base0 + k] = q0[k];
        const unsigned int* q1 = ebuf + j1 * EPB + s1;
        for (int k = 0; k < l1; k++) lbuf[base1 + k] = q1[k];
        __syncthreads();
        for (int k = t; k < total; k += 256) atomicAdd(&lhist[lbuf[k] >> 16], 1);
    } else {
        const unsigned int* q0 = ebuf + j0 * EPB + s0;
        for (int k = 0; k < l0; k++) atomicAdd(&lhist[q0[k] >> 16], 1);
        const unsigned int* q1 = ebuf + j1 * EPB + s1;
        for (int k = 0; k < l1; k++) atomicAdd(&lhist[q1[k] >> 16], 1);
    }
    __syncthreads();
    int v = lhist[t];
    ls[t] = v;
    __syncthreads();
    #pragma unroll
    for (int d = 1; d < 256; d <<= 1) {
        int u = (t >= d) ? ls[t - d] : 0;
        __syncthreads();
        ls[t] += u;
        __syncthreads();
    }
    int ex = ls[t] - v;
    lcur[t] = ex;
    if (t < nnodes) {
        cnt[node0 + t] = v;
        off[node0 + t] = segBase + ex;
        dinv[node0 + t] = rsqrtf((float)v + 1.0f);
    }
    __syncthreads();
    if (fits) {
        for (int k = t; k < total; k += 256) {
            unsigned int pp = lbuf[k];
            int lp = atomicAdd(&lcur[pp >> 16], 1);
            esrc[segBase + lp] = (unsigned short)(pp & 0xFFFFu);
        }
    } else {
        const unsigned int* q0 = ebuf + j0 * EPB + s0;
        for (int k = 0; k < l0; k++) {
            unsigned int pp = q0[k];
            int lp = atomicAdd(&lcur[pp >> 16], 1);
            esrc[segBase + lp] = (unsigned short)(pp & 0xFFFFu);
        }
        const unsigned int* q1 = ebuf + j1 * EPB + s1;
        for (int k = 0; k < l1; k++) {
            unsigned int pp = q1[k];
            int lp = atomicAdd(&lcur[pp >> 16], 1);
            esrc[segBase + lp] = (unsigned short)(pp & 0xFFFFu);
        }
    }
}

// ---------------- K3: gather1 — wave-per-node whole-row + batched per-edge dinv -------------
// g1 is UNSCALED. msg(s->n) = dinv[s]*g1[s]; self = dinv[n]*g1[n]; out = dinv[n]*SUM + b.
// dinv[vidx] batch-loaded with the index batch (L2-resident 200 KB), broadcast via shfl;
// fmaf replaces add at zero VALU cost.
__global__ __launch_bounds__(256) void gather1_kernel(const unsigned short* __restrict__ g1,
                                                      const unsigned short* __restrict__ esrc,
                                                      const int* __restrict__ off,
                                                      const int* __restrict__ cnt,
                                                      const float* __restrict__ dinv,
                                                      const float* __restrict__ b1,
                                                      unsigned short* __restrict__ x2) {
    const int n = blockIdx.x * 4 + (threadIdx.x >> 6);
    if (n >= NN) return;
    const int lane = threadIdx.x & 63;
    const unsigned int* G = (const unsigned int*)g1;   // row stride 64 uints (256 B)
    const float dn = dinv[n];
    float2 ps = bf2f(G[(size_t)n * 64 + lane]);
    float a0 = dn * ps.x, a1 = dn * ps.y;              // self-loop (x dn again at the end)
    float c0 = 0.f, c1 = 0.f;
    const int s0 = off[n], c = cnt[n];
    for (int base = 0; base < c; base += 64) {
        const int m = min(64, c - base);
        int vidx = 0; float vdin = 0.f;
        if (lane < m) {
            vidx = esrc[s0 + base + lane];             // coalesced 128 B index batch
            vdin = dinv[vidx];                         // batched per-src dinv (L2 hit)
        }
        int i = 0;
        for (; i + 3 < m; i += 4) {
            int sA = __shfl(vidx, i),     sB = __shfl(vidx, i + 1);
            int sC = __shfl(vidx, i + 2), sD = __shfl(vidx, i + 3);
            float dA = __shfl(vdin, i),     dB = __shfl(vdin, i + 1);
            float dC = __shfl(vdin, i + 2), dD = __shfl(vdin, i + 3);
            unsigned int vA = G[(size_t)sA * 64 + lane];
            unsigned int vB = G[(size_t)sB * 64 + lane];
            unsigned int vC = G[(size_t)sC * 64 + lane];
            unsigned int vD = G[(size_t)sD * 64 + lane];
            float2 pA = bf2f(vA); a0 = fmaf(dA, pA.x, a0); a1 = fmaf(dA, pA.y, a1);
            float2 pB = bf2f(vB); c0 = fmaf(dB, pB.x, c0); c1 = fmaf(dB, pB.y, c1);
            float2 pC = bf2f(vC); a0 = fmaf(dC, pC.x, a0); a1 = fmaf(dC, pC.y, a1);
            float2 pD = bf2f(vD); c0 = fmaf(dD, pD.x, c0); c1 = fmaf(dD, pD.y, c1);
        }
        for (; i < m; i++) {
            int sA = __shfl(vidx, i);
            float dA = __shfl(vdin, i);
            float2 pA = bf2f(G[(size_t)sA * 64 + lane]);
            a0 = fmaf(dA, pA.x, a0); a1 = fmaf(dA, pA.y, a1);
        }
    }
    a0 += c0; a1 += c1;
    const float2 bb = ((const float2*)b1)[lane];
    const float o0 = fmaxf(dn * a0 + bb.x, 0.f);
    const float o1 = fmaxf(dn * a1 + bb.y, 0.f);
    ((unsigned int*)x2)[(size_t)n * 64 + lane] = pk2(o0, o1);   // 256 B coalesced store
}

// ---------------- K4: mm2 — g2(bf16 row-major) = dinv * (x2 @ W2) ---------------------------
__global__ __launch_bounds__(256, 2) void mm2_kernel(const unsigned short* __restrict__ x2,
                                                     const float* __restrict__ W,
                                                     const float* __restrict__ dinv,
                                                     unsigned short* __restrict__ g2) {
    __shared__ unsigned short wl[4][4][64][8];   // 16 KB
    const int t = threadIdx.x;
    for (int i = 0; i < 32; i++) {
        int idx = i * 256 + t;
        int k = idx >> 6, n = idx & 63;
        wl[k >> 5][n >> 4][((k >> 3) & 3) * 16 + (n & 15)][k & 7] = f2bf(W[idx]);
    }
    __syncthreads();
    const int lane = t & 63, lm = lane & 15, quad = lane >> 4;

    bf16x8 bfr[4][4];
    #pragma unroll
    for (int s = 0; s < 4; s++)
        #pragma unroll
        for (int nt = 0; nt < 4; nt++)
            bfr[s][nt] = *(const bf16x8*)&wl[s][nt][lane][0];

    int wg = blockIdx.x * 4 + (t >> 6);
    for (int tile = wg; tile < MT; tile += MMWAVES) {
        int row0 = tile << 4;
        const bf16x8* xr = (const bf16x8*)(x2 + (size_t)(row0 + lm) * 128 + quad * 8);
        bf16x8 af[4];
        #pragma unroll
        for (int s = 0; s < 4; s++) af[s] = xr[s * 4];
        f32x4 acc[4];
        #pragma unroll
        for (int nt = 0; nt < 4; nt++) acc[nt] = (f32x4){0.f, 0.f, 0.f, 0.f};
        #pragma unroll
        for (int s = 0; s < 4; s++)
            #pragma unroll
            for (int nt = 0; nt < 4; nt++)
                acc[nt] = __builtin_amdgcn_mfma_f32_16x16x32_bf16(af[s], bfr[s][nt],
                                                                  acc[nt], 0, 0, 0);
        float4 dv = *(const float4*)(dinv + row0 + quad * 4);
        float dvv[4] = {dv.x, dv.y, dv.z, dv.w};
        #pragma unroll
        for (int nt = 0; nt < 4; nt++)
            #pragma unroll
            for (int r = 0; r < 4; r++)
                g2[(size_t)(row0 + quad * 4 + r) * 64 + nt * 16 + lm] =
                    f2bf(acc[nt][r] * dvv[r]);
    }
}

// ---------------- K5: gather2 — wave-per-node whole-row (128 B) coalesced, fp32 out ---------
__global__ __launch_bounds__(256) void gather2_kernel(const unsigned short* __restrict__ g2,
                                                      const unsigned short* __restrict__ esrc,
                                                      const int* __restrict__ off,
                                                      const int* __restrict__ cnt,
                                                      const float* __restrict__ dinv,
                                                      const float* __restrict__ b2,
                                                      float* __restrict__ out) {
    const int n = blockIdx.x * 4 + (threadIdx.x >> 6);
    if (n >= NN) return;
    const int lane = threadIdx.x & 63;
    const unsigned short* G = g2;                      // row stride 64 ushorts (128 B)
    float a0 = __uint_as_float((unsigned int)G[(size_t)n * 64 + lane] << 16);  // self-loop
    float c0 = 0.f;
    const int s0 = off[n], c = cnt[n];
    for (int base = 0; base < c; base += 64) {
        const int m = min(64, c - base);
        int vidx = 0;
        if (lane < m) vidx = esrc[s0 + base + lane];
        int i = 0;
        for (; i + 3 < m; i += 4) {
            int sA = __shfl(vidx, i),     sB = __shfl(vidx, i + 1);
            int sC = __shfl(vidx, i + 2), sD = __shfl(vidx, i + 3);
            unsigned short vA = G[(size_t)sA * 64 + lane];
            unsigned short vB = G[(size_t)sB * 64 + lane];
            unsigned short vC = G[(size_t)sC * 64 + lane];
            unsigned short vD = G[(size_t)sD * 64 + lane];
            a0 += __uint_as_float((unsigned int)vA << 16);
            c0 += __uint_as_float((unsigned int)vB << 16);
            a0 += __uint_as_float((unsigned int)vC << 16);
            c0 += __uint_as_float((unsigned int)vD << 16);
        }
        for (; i < m; i++) {
            int sA = __shfl(vidx, i);
            a0 += __uint_as_float((unsigned int)G[(size_t)sA * 64 + lane] << 16);
        }
    }
    a0 += c0;
    out[(size_t)n * 64 + lane] = dinv[n] * a0 + b2[lane];   // 256 B coalesced store
}

extern "C" void kernel_launch(void* const* d_in, const int* in_sizes, int n_in,
                              void* d_out, int out_size, void* d_ws, size_t ws_size,
                              hipStream_t stream) {
    const float* x  = (const float*)d_in[0];
    const int* edges = (const int*)d_in[1];     // [2, NE] int32
    const float* W1 = (const float*)d_in[2];
    const float* b1 = (const float*)d_in[3];
    const float* W2 = (const float*)d_in[4];
    const float* b2 = (const float*)d_in[5];
    const int* src = edges;
    const int* dst = edges + NE;

    // workspace layout (all chunks 16B-aligned)
    int* localOff  = (int*)d_ws;                        // NBLK*200 = 78200, pad 78208
    unsigned int* ebuf = (unsigned int*)(localOff + 78208);   // NBLK*EPB = 800768
    unsigned short* esrc = (unsigned short*)(ebuf + (size_t)NBLK * EPB);  // 800000 u16, pad 800768
    int* cnt       = (int*)(esrc + 800768);             // 50048
    int* off       = cnt + 50048;                       // 50048
    float* dinv    = (float*)(off + 50048);             // 50048
    unsigned short* g1 = (unsigned short*)(dinv + 50048);   // [NN][128] bf16 row-major UNSCALED
    unsigned short* x2 = g1 + (size_t)NN * C1;              // [NN][128] bf16 row-major
    unsigned short* g2 = g1;                            // alias: g1 dead before mm2
    float* out = (float*)d_out;

    // K1: CSR bin || all of mm1 (g1 unscaled -> independent of CSR)
    k1_kernel<<<K1G, 256, 0, stream>>>(src, dst, ebuf, localOff, x, W1, g1);
    // K2: CSR place (esrc/cnt/off/dinv)
    place_kernel<<<NBK, 256, 0, stream>>>(ebuf, localOff, esrc, cnt, off, dinv);
    // K3: gather1 (per-edge dinv, batched)
    gather1_kernel<<<GB, 256, 0, stream>>>(g1, esrc, off, cnt, dinv, b1, x2);
    // K4: mm2
    mm2_kernel<<<MMB, 256, 0, stream>>>(x2, W2, dinv, g2);
    // K5: gather2 -> out
    gather2_kernel<<<GB, 256, 0, stream>>>(g2, esrc, off, cnt, dinv, b2, out);
}